// Round 6
// baseline (5998.170 us; speedup 1.0000x reference)
//
#include <hip/hip_runtime.h>

typedef __attribute__((ext_vector_type(8))) short short8;
typedef __attribute__((ext_vector_type(4))) float f32x4;
typedef unsigned int uint32;
typedef unsigned long long u64;

// ---------- workspace layout (bytes) ----------
// gi region: gemm0 writes gi0 [512][64][4096] (natural gate layout). During the
//   fused phase-0 kernel, PRODUCER WGs write gi1[t] (gate-interleaved, np=c*4+g)
//   IN-PLACE over gi0[t] with NORMAL stores — gated on cg[t]==64, i.e. after the
//   whole p-group consumed gi0[t] (certified by round 5, which used the same
//   in-place pattern incl. cross-XCD stale-clean lines resolved at the kernel
//   boundary before rec1's cached reads).
// cnt/hbuf: virgin region (SDMA memset + atomics only) — round-0-certified
//   sync channel. cnt[4][2048]: per p-group, ints [0,512) = cg (h-ready),
//   ints [1024,1536) = pr (producer staged y0(t) -> hbuf slot reusable).
#define OFF_GI    0ull                 // 268,435,456  bf16 gi0 / gi1 (in-place)
#define OFF_XB    268435456ull         //  67,108,864  bf16 x (gemm0 input only)
#define OFF_WIH0  335544320ull         //   8,388,608  bf16 w_ih_0
#define OFF_WPKI  343932928ull         //   8,388,608  packed w_ih_1 gi1-fragments
#define OFF_WPK0  352321536ull         //   8,388,608  packed w_hh_0 frags
#define OFF_WPK1  360710144ull         //   8,388,608  packed w_hh_1 frags
#define OFF_B0    369098752ull         //      16,384  fp32 bias sum layer0 (natural)
#define OFF_B1    369115136ull         //      16,384  fp32 bias sum layer1 (PERM c*4+g)
#define OFF_CNT   369131520ull         //      32,768  int cnt[4][2048]
#define OFF_HBUF  369164288ull         //     262,144  bf16 h double-buffer [2][64][1024]
#define WS_REQUIRED 369426432ull       // proven size

#define ALOAD(p)    __hip_atomic_load((p), __ATOMIC_RELAXED, __HIP_MEMORY_SCOPE_AGENT)
#define ASTOREV(p,v) __hip_atomic_store((p), (v), __ATOMIC_RELAXED, __HIP_MEMORY_SCOPE_AGENT)
#define AADD(p,v)   __hip_atomic_fetch_add((p), (v), __ATOMIC_RELAXED, __HIP_MEMORY_SCOPE_AGENT)
#define WD_ITERS 30000   // bounds worst-case broken-sync runtime to well under 1 s

// ---------- helpers ----------
__device__ __forceinline__ unsigned short f2bf(float f) {
    union { float f; uint32 u; } v; v.f = f;
    uint32 u = v.u + 0x7FFFu + ((v.u >> 16) & 1u);   // round-to-nearest-even
    return (unsigned short)(u >> 16);
}
__device__ __forceinline__ float bf2f(unsigned short u) {
    union { uint32 u; float f; } v; v.u = ((uint32)u) << 16; return v.f;
}
__device__ __forceinline__ float sigmoidf_(float x) {
    return 1.0f / (1.0f + __expf(-x));
}
__device__ __forceinline__ float tanhf_(float x) {
    return 1.0f - 2.0f / (1.0f + __expf(2.0f * x));
}

// ---------- diagnostic ----------
__global__ void diag_kernel(float* out, float val) {
    if (blockIdx.x == 0 && threadIdx.x == 0) out[0] = val;
}

// ---------- small prep kernels ----------
__global__ void cast_bf16_kernel(const float* __restrict__ in,
                                 unsigned short* __restrict__ out, int n4) {
    int i = blockIdx.x * 256 + threadIdx.x;
    if (i < n4) {
        float4 v = ((const float4*)in)[i];
        ushort4 o;
        o.x = f2bf(v.x); o.y = f2bf(v.y); o.z = f2bf(v.z); o.w = f2bf(v.w);
        ((ushort4*)out)[i] = o;
    }
}

__global__ void bias_sum_kernel(const float* __restrict__ a,
                                const float* __restrict__ b,
                                float* __restrict__ o, int n) {
    int i = blockIdx.x * 256 + threadIdx.x;
    if (i < n) o[i] = a[i] + b[i];
}

// layer-1 bias in gate-interleaved order: o[c*4+g] = bih1[g*1024+c]+bhh1[g*1024+c]
__global__ void bias_perm_kernel(const float* __restrict__ a,
                                 const float* __restrict__ b,
                                 float* __restrict__ o) {
    int i = blockIdx.x * 256 + threadIdx.x;   // 4096
    int c = i >> 2, g = i & 3;
    o[i] = a[g * 1024 + c] + b[g * 1024 + c];
}

// Pack w_hh [4096][1024] fp32 into per-(WG,wave) MFMA B-fragment order, bf16.
__global__ void pack_whh_kernel(const float* __restrict__ whh,
                                unsigned short* __restrict__ out) {
    int o = blockIdx.x * 256 + threadIdx.x;   // 4,194,304 total
    int j  = o & 7;
    int l  = (o >> 3) & 63;
    int f  = (o >> 9) & 31;
    int wq = o >> 14;
    int w = wq >> 2, q = wq & 3;
    int g = f >> 3,  s = f & 7;
    int n = g * 1024 + w * 16 + (l & 15);
    int k = q * 256 + s * 32 + ((l >> 4)) * 8 + j;
    out[o] = f2bf(whh[(size_t)n * 1024 + k]);
}

// Pack w_ih_1 [4096][1024] fp32 into gi1-GEMM B-fragments, gate-interleaved cols.
// (certified by round 5)
__global__ void pack_wih1_frag_kernel(const float* __restrict__ wih1,
                                      unsigned short* __restrict__ out) {
    int o = blockIdx.x * 256 + threadIdx.x;   // 4,194,304 total
    int j  = o & 7;
    int l  = (o >> 3) & 63;
    int ks = (o >> 9) & 31;
    int wq = o >> 14;
    int w = wq >> 2, q = wq & 3;
    int np = w * 64 + q * 16 + (l & 15);
    int c = np >> 2, g = np & 3;
    int k = ks * 32 + ((l >> 4)) * 8 + j;
    out[o] = f2bf(wih1[(size_t)(g * 1024 + c) * 1024 + k]);
}

// ---------- layer-0 input GEMM (unchanged, proven) ----------
__global__ __launch_bounds__(256, 2) void gemm_bt_kernel(
    const unsigned short* __restrict__ A,
    const unsigned short* __restrict__ B,
    const float* __restrict__ bias,
    unsigned short* __restrict__ C) {
    __shared__ __align__(16) unsigned short As[128 * 64];
    __shared__ __align__(16) unsigned short Bs[128 * 64];
    const int tid = threadIdx.x;
    const int l = tid & 63;
    const int wv = tid >> 6;
    const int wm = wv >> 1, wn = wv & 1;
    const long bm = blockIdx.x, bn = blockIdx.y;

    f32x4 acc[4][4];
#pragma unroll
    for (int i = 0; i < 4; ++i)
#pragma unroll
        for (int j = 0; j < 4; ++j)
            acc[i][j] = (f32x4){0.f, 0.f, 0.f, 0.f};

    for (int k0 = 0; k0 < 1024; k0 += 64) {
#pragma unroll
        for (int ii = 0; ii < 4; ++ii) {
            int slot = ii * 256 + tid;
            int row = slot >> 3, csw = slot & 7;
            int cc = csw ^ (row & 7);
            *(uint4*)&As[slot * 8] =
                *(const uint4*)(A + (bm * 128 + row) * 1024 + k0 + cc * 8);
            *(uint4*)&Bs[slot * 8] =
                *(const uint4*)(B + (bn * 128 + row) * 1024 + k0 + cc * 8);
        }
        __syncthreads();
#pragma unroll
        for (int s = 0; s < 2; ++s) {
            short8 af[4], bfm[4];
#pragma unroll
            for (int i = 0; i < 4; ++i) {
                int row = wm * 64 + i * 16 + (l & 15);
                af[i] = *(const short8*)&As[(row * 8 + (((s * 4) + (l >> 4)) ^ (row & 7))) * 8];
            }
#pragma unroll
            for (int j = 0; j < 4; ++j) {
                int row = wn * 64 + j * 16 + (l & 15);
                bfm[j] = *(const short8*)&Bs[(row * 8 + (((s * 4) + (l >> 4)) ^ (row & 7))) * 8];
            }
#pragma unroll
            for (int i = 0; i < 4; ++i)
#pragma unroll
                for (int j = 0; j < 4; ++j)
                    acc[i][j] = __builtin_amdgcn_mfma_f32_16x16x32_bf16(
                        af[i], bfm[j], acc[i][j], 0, 0, 0);
        }
        __syncthreads();
    }
#pragma unroll
    for (int j = 0; j < 4; ++j) {
        float bj = bias[bn * 128 + wn * 64 + j * 16 + (l & 15)];
#pragma unroll
        for (int i = 0; i < 4; ++i) {
#pragma unroll
            for (int r = 0; r < 4; ++r) {
                long row = bm * 128 + wm * 64 + i * 16 + (l >> 4) * 4 + r;
                C[row * 4096 + bn * 128 + wn * 64 + j * 16 + (l & 15)] =
                    f2bf(acc[i][j][r] + bj);
            }
        }
    }
}

// ---------- gi1 tile (certified round 5): 16 rows x 16 cols' per wave, k=1024 ----------
__device__ __forceinline__ void gi1_tile(
    const unsigned short* hs,
    const unsigned short* __restrict__ wpkI,
    const float* __restrict__ b1p,
    unsigned short* gi1,
    int tg, int p, int w, int q, int l)
{
    f32x4 gacc = (f32x4){0.f, 0.f, 0.f, 0.f};
    const int arow = l & 15;
    const unsigned short* wb = wpkI + (size_t)(w * 4 + q) * 16384 + (size_t)l * 8;
#pragma unroll 4
    for (int ks = 0; ks < 32; ++ks) {
        short8 bfk = *(const short8*)(wb + ks * 512);
        short8 afk = *(const short8*)&hs[(arow * 128 + ((ks * 4 + (l >> 4)) ^ (arow & 7))) * 8];
        gacc = __builtin_amdgcn_mfma_f32_16x16x32_bf16(afk, bfk, gacc, 0, 0, 0);
    }
    const int colp = w * 64 + q * 16 + (l & 15);
    float bj = b1p[colp];
#pragma unroll
    for (int r = 0; r < 4; ++r) {
        int v0 = f2bf(gacc[r] + bj);
        int v1 = __shfl_down(v0, 1);
        int v2 = __shfl_down(v0, 2);
        int v3 = __shfl_down(v0, 3);
        if ((l & 3) == 0) {
            size_t row = (size_t)tg * 64 + p * 16 + (l >> 4) * 4 + r;
            u64 u = (u64)(v0 & 0xffff) | ((u64)(v1 & 0xffff) << 16) |
                    ((u64)(v2 & 0xffff) << 32) | ((u64)(v3 & 0xffff) << 48);
            *(u64*)(gi1 + row * 4096 + colp) = u;
        }
    }
}

// ---------- fused phase 0: 256 consumer WGs (rec0) + 256 producer WGs (gi1) ----------
// One-directional dependencies only:
//   producer step t  <- cg[t]   (all consumers of group p finished step t)
//   consumer step t  <- cg[t-1] (round-0 proven), pr[t-2] (producers done with
//                      hbuf slot (t+1)&1's current content y0(t-2))
// Producers never block consumers beyond a 2-step-stale, always-resolved check.
__global__ __launch_bounds__(256, 2) void lstm_l0_fused_kernel(
    unsigned short* gi,                      // consumer: gi0 cached reads; producer: gi1 normal writes
    const unsigned short* __restrict__ wpk0,
    const unsigned short* __restrict__ wpkI,
    const float* __restrict__ b1p,
    unsigned short* hbuf,                    // [2][64][1024] bf16 (virgin atomic region)
    float* __restrict__ hn, float* __restrict__ cn,
    int* cnt)
{
    __shared__ __align__(16) char smem[49152];
    const int bid = blockIdx.x;
    const int tid = threadIdx.x;
    const int l = tid & 63, q = tid >> 6;

    if (bid < 256) {
        // ---------------- consumer: round-0 recurrence, byte-exact ----------------
        unsigned short* hs = (unsigned short*)smem;                      // 32 KB
        float (*red)[4][16][16] = (float (*)[4][16][16])(smem + 32768);  // 16 KB
        const int p = bid >> 6, w = bid & 63;
        int* cg = cnt + p * 2048;
        int* pr = cnt + p * 2048 + 1024;

        short8 bfr[4][8];
        {
            const unsigned short* wb = wpk0 + (size_t)((w * 4 + q) * 32) * 512 + (size_t)l * 8;
#pragma unroll
            for (int g = 0; g < 4; ++g)
#pragma unroll
                for (int s = 0; s < 8; ++s)
                    bfr[g][s] = *(const short8*)(wb + (g * 8 + s) * 512);
        }

        float c_state = 0.0f;
        const int be = tid >> 4, je = tid & 15;
        const int hrow = p * 16 + be;
        const int hcol = w * 16 + je;

        for (int t = 0; t < 512; ++t) {
            // prefetch gi0[t] (cached; producers overwrite these bytes only
            // after cg[t]==64, i.e. after this step completes)
            const unsigned short* gp = gi + (size_t)t * 262144 + (size_t)hrow * 4096 + hcol;
            float g0 = bf2f(gp[0]);
            float g1 = bf2f(gp[1024]);
            float g2 = bf2f(gp[2048]);
            float g3 = bf2f(gp[3072]);

            if (tid == 0) {
                if (t > 0) {
                    int iters = 0;
                    while (ALOAD(&cg[t - 1]) < 64) {
                        __builtin_amdgcn_s_sleep(2);
                        if (++iters > WD_ITERS) break;
                    }
                }
                if (t >= 2) {
                    // hbuf slot (t+1)&1 currently holds y0(t-2); producers must
                    // have staged it before this step's publish overwrites it.
                    int iters = 0;
                    while (ALOAD(&pr[t - 2]) < 64) {
                        __builtin_amdgcn_s_sleep(2);
                        if (++iters > WD_ITERS) break;
                    }
                }
            }
            __syncthreads();                                              // B1

            // stage h(t-1) rows [16p,16p+16), XOR-swizzled, atomic b64
            {
                const u64* hp64 = (const u64*)(hbuf + (size_t)(t & 1) * 65536);
#pragma unroll
                for (int ii = 0; ii < 8; ++ii) {
                    int slot = ii * 256 + tid;
                    int row = slot >> 7, cs = slot & 127;
                    int cc = cs ^ (row & 7);
                    size_t gidx = ((size_t)(p * 16 + row) * 1024 + (size_t)cc * 8) >> 2;
                    u64 lo = ALOAD(&hp64[gidx]);
                    u64 hi = ALOAD(&hp64[gidx + 1]);
                    *(u64*)&hs[slot * 8]     = lo;
                    *(u64*)&hs[slot * 8 + 4] = hi;
                }
            }
            __syncthreads();                                              // B2

            // h-GEMM: wave q covers k in [256q, 256q+256)
            f32x4 acc[4];
#pragma unroll
            for (int g = 0; g < 4; ++g) acc[g] = (f32x4){0.f, 0.f, 0.f, 0.f};
            const int arow = l & 15;
#pragma unroll
            for (int s = 0; s < 8; ++s) {
                int chunk = q * 32 + s * 4 + (l >> 4);
                short8 af = *(const short8*)&hs[(arow * 128 + (chunk ^ (arow & 7))) * 8];
#pragma unroll
                for (int g = 0; g < 4; ++g)
                    acc[g] = __builtin_amdgcn_mfma_f32_16x16x32_bf16(
                        af, bfr[g][s], acc[g], 0, 0, 0);
            }
#pragma unroll
            for (int g = 0; g < 4; ++g)
#pragma unroll
                for (int r = 0; r < 4; ++r)
                    red[q][g][(l >> 4) * 4 + r][l & 15] = acc[g][r];
            __syncthreads();                                              // B3

            float gate_i = g0, gate_f = g1, gate_g = g2, gate_o = g3;
#pragma unroll
            for (int qq = 0; qq < 4; ++qq) {
                gate_i += red[qq][0][be][je];
                gate_f += red[qq][1][be][je];
                gate_g += red[qq][2][be][je];
                gate_o += red[qq][3][be][je];
            }
            float ig = sigmoidf_(gate_i);
            float fg = sigmoidf_(gate_f);
            float gg = tanhf_(gate_g);
            float og = sigmoidf_(gate_o);
            c_state = fg * c_state + ig * gg;
            float h_new = og * tanhf_(c_state);

            unsigned short hb = f2bf(h_new);
            {
                int v0 = hb;
                int v1 = __shfl_down(v0, 1);
                int v2 = __shfl_down(v0, 2);
                int v3 = __shfl_down(v0, 3);
                if ((l & 3) == 0) {
                    u64 u = (u64)(v0 & 0xffff) | ((u64)(v1 & 0xffff) << 16) |
                            ((u64)(v2 & 0xffff) << 32) | ((u64)(v3 & 0xffff) << 48);
                    u64* dst = (u64*)(hbuf + (size_t)((t + 1) & 1) * 65536 +
                                      (size_t)hrow * 1024 + hcol);
                    ASTOREV(dst, u);
                }
            }
            if (t == 511) {
                hn[(size_t)hrow * 1024 + hcol] = h_new;
                cn[(size_t)hrow * 1024 + hcol] = c_state;
            }
            __syncthreads();   // B4: vmcnt(0) drain -> h stores at the IC
            if (tid == 0) AADD(&cg[t], 1);
        }
    } else {
        // ---------------- producer: gi1[t] = y0(t) @ w_ih_1p^T + b1p ----------------
        unsigned short* hs = (unsigned short*)smem;                      // 32 KB
        const int W = bid - 256;
        const int p = W >> 6, w = W & 63;
        int* cg = cnt + p * 2048;
        int* pr = cnt + p * 2048 + 1024;

        for (int t = 0; t < 512; ++t) {
            if (tid == 0) {
                int iters = 0;   // y0(t) published by all consumers of group p
                while (ALOAD(&cg[t]) < 64) {
                    __builtin_amdgcn_s_sleep(2);
                    if (++iters > WD_ITERS) break;
                }
            }
            __syncthreads();

            // stage y0(t) = hbuf slot (t+1)&1 rows [16p,16p+16) (certified code)
            {
                const u64* hp64 = (const u64*)(hbuf + (size_t)((t + 1) & 1) * 65536);
#pragma unroll
                for (int ii = 0; ii < 8; ++ii) {
                    int slot = ii * 256 + tid;
                    int row = slot >> 7, cs = slot & 127;
                    int cc = cs ^ (row & 7);
                    size_t gidx = ((size_t)(p * 16 + row) * 1024 + (size_t)cc * 8) >> 2;
                    u64 lo = ALOAD(&hp64[gidx]);
                    u64 hi = ALOAD(&hp64[gidx + 1]);
                    *(u64*)&hs[slot * 8]     = lo;
                    *(u64*)&hs[slot * 8 + 4] = hi;
                }
            }
            __syncthreads();
            if (tid == 0) AADD(&pr[t], 1);   // hbuf slot content consumed

            // gi1[t] in place over gi0[t] (normal stores; certified pattern)
            gi1_tile(hs, wpkI, b1p, gi, t, p, w, q, l);
        }
    }
}

// ---------- layer-1 recurrence (round-5 certified, unchanged) ----------
__global__ __launch_bounds__(256, 2) void lstm_rec1_kernel(
    const unsigned short* __restrict__ gi,   // gate-interleaved gi1 (cached reads)
    const unsigned short* __restrict__ wpk,
    unsigned short* hbuf,
    float* __restrict__ yf,
    float* __restrict__ hn, float* __restrict__ cn,
    int* cnt) {
    __shared__ __align__(16) unsigned short hs[16 * 1024];
    __shared__ float red[4][4][16][16];
    const int tid = threadIdx.x;
    const int l = tid & 63, q = tid >> 6;
    const int W = blockIdx.x;
    const int p = W >> 6, w = W & 63;
    int* cg = cnt + p * 2048;

    short8 bfr[4][8];
    {
        const unsigned short* wb = wpk + (size_t)((w * 4 + q) * 32) * 512 + (size_t)l * 8;
#pragma unroll
        for (int g = 0; g < 4; ++g)
#pragma unroll
            for (int s = 0; s < 8; ++s)
                bfr[g][s] = *(const short8*)(wb + (g * 8 + s) * 512);
    }

    float c_state = 0.0f;
    const int be = tid >> 4, je = tid & 15;
    const int hrow = p * 16 + be;
    const int hcol = w * 16 + je;

    for (int t = 0; t < 512; ++t) {
        u64 gv = *(const u64*)(gi + ((size_t)t * 64 + hrow) * 4096 + (size_t)hcol * 4);
        float g0 = bf2f((unsigned short)gv);
        float g1 = bf2f((unsigned short)(gv >> 16));
        float g2 = bf2f((unsigned short)(gv >> 32));
        float g3 = bf2f((unsigned short)(gv >> 48));

        if (t > 0 && tid == 0) {
            int iters = 0;
            while (ALOAD(&cg[t - 1]) < 64) {
                __builtin_amdgcn_s_sleep(2);
                if (++iters > WD_ITERS) break;
            }
        }
        __syncthreads();

        {
            const u64* hp64 = (const u64*)(hbuf + (size_t)(t & 1) * 65536);
#pragma unroll
            for (int ii = 0; ii < 8; ++ii) {
                int slot = ii * 256 + tid;
                int row = slot >> 7, cs = slot & 127;
                int cc = cs ^ (row & 7);
                size_t gidx = ((size_t)(p * 16 + row) * 1024 + (size_t)cc * 8) >> 2;
                u64 lo = ALOAD(&hp64[gidx]);
                u64 hi = ALOAD(&hp64[gidx + 1]);
                *(u64*)&hs[slot * 8]     = lo;
                *(u64*)&hs[slot * 8 + 4] = hi;
            }
        }
        __syncthreads();

        f32x4 acc[4];
#pragma unroll
        for (int g = 0; g < 4; ++g) acc[g] = (f32x4){0.f, 0.f, 0.f, 0.f};
        const int arow = l & 15;
#pragma unroll
        for (int s = 0; s < 8; ++s) {
            int chunk = q * 32 + s * 4 + (l >> 4);
            short8 af = *(const short8*)&hs[(arow * 128 + (chunk ^ (arow & 7))) * 8];
#pragma unroll
            for (int g = 0; g < 4; ++g)
                acc[g] = __builtin_amdgcn_mfma_f32_16x16x32_bf16(
                    af, bfr[g][s], acc[g], 0, 0, 0);
        }
#pragma unroll
        for (int g = 0; g < 4; ++g)
#pragma unroll
            for (int r = 0; r < 4; ++r)
                red[q][g][(l >> 4) * 4 + r][l & 15] = acc[g][r];
        __syncthreads();

        float gate_i = g0, gate_f = g1, gate_g = g2, gate_o = g3;
#pragma unroll
        for (int qq = 0; qq < 4; ++qq) {
            gate_i += red[qq][0][be][je];
            gate_f += red[qq][1][be][je];
            gate_g += red[qq][2][be][je];
            gate_o += red[qq][3][be][je];
        }
        float ig = sigmoidf_(gate_i);
        float fg = sigmoidf_(gate_f);
        float gg = tanhf_(gate_g);
        float og = sigmoidf_(gate_o);
        c_state = fg * c_state + ig * gg;
        float h_new = og * tanhf_(c_state);

        unsigned short hb = f2bf(h_new);
        {
            int v0 = hb;
            int v1 = __shfl_down(v0, 1);
            int v2 = __shfl_down(v0, 2);
            int v3 = __shfl_down(v0, 3);
            if ((l & 3) == 0) {
                u64 u = (u64)(v0 & 0xffff) | ((u64)(v1 & 0xffff) << 16) |
                        ((u64)(v2 & 0xffff) << 32) | ((u64)(v3 & 0xffff) << 48);
                u64* dst = (u64*)(hbuf + (size_t)((t + 1) & 1) * 65536 +
                                  (size_t)hrow * 1024 + hcol);
                ASTOREV(dst, u);
            }
        }
        yf[(size_t)t * 65536 + (size_t)hrow * 1024 + hcol] = h_new;
        if (t == 511) {
            hn[(size_t)hrow * 1024 + hcol] = h_new;
            cn[(size_t)hrow * 1024 + hcol] = c_state;
        }
        __syncthreads();
        if (tid == 0) AADD(&cg[t], 1);
    }
}

// ---------- launcher ----------
extern "C" void kernel_launch(void* const* d_in, const int* in_sizes, int n_in,
                              void* d_out, int out_size, void* d_ws, size_t ws_size,
                              hipStream_t stream) {
    const float* x    = (const float*)d_in[0];
    const float* wih0 = (const float*)d_in[1];
    const float* whh0 = (const float*)d_in[2];
    const float* bih0 = (const float*)d_in[3];
    const float* bhh0 = (const float*)d_in[4];
    const float* wih1 = (const float*)d_in[5];
    const float* whh1 = (const float*)d_in[6];
    const float* bih1 = (const float*)d_in[7];
    const float* bhh1 = (const float*)d_in[8];
    float* out = (float*)d_out;

    if (ws_size < WS_REQUIRED) {
        diag_kernel<<<1, 64, 0, stream>>>(out, (float)(ws_size >> 20));
        return;
    }

    char* ws = (char*)d_ws;
    unsigned short* gi    = (unsigned short*)(ws + OFF_GI);
    unsigned short* xb    = (unsigned short*)(ws + OFF_XB);
    unsigned short* wih0b = (unsigned short*)(ws + OFF_WIH0);
    unsigned short* wpkI  = (unsigned short*)(ws + OFF_WPKI);
    unsigned short* wpk0  = (unsigned short*)(ws + OFF_WPK0);
    unsigned short* wpk1  = (unsigned short*)(ws + OFF_WPK1);
    float*          b0    = (float*)(ws + OFF_B0);
    float*          b1p   = (float*)(ws + OFF_B1);
    int*            cnt   = (int*)(ws + OFF_CNT);
    unsigned short* hbuf  = (unsigned short*)(ws + OFF_HBUF);

    // prep
    cast_bf16_kernel<<<32768, 256, 0, stream>>>(x, xb, 8388608);
    cast_bf16_kernel<<<4096, 256, 0, stream>>>(wih0, wih0b, 1048576);
    pack_wih1_frag_kernel<<<16384, 256, 0, stream>>>(wih1, wpkI);
    pack_whh_kernel<<<16384, 256, 0, stream>>>(whh0, wpk0);
    pack_whh_kernel<<<16384, 256, 0, stream>>>(whh1, wpk1);
    bias_sum_kernel<<<16, 256, 0, stream>>>(bih0, bhh0, b0, 4096);
    bias_perm_kernel<<<16, 256, 0, stream>>>(bih1, bhh1, b1p);

    // layer-0 input projection
    gemm_bt_kernel<<<dim3(256, 32), 256, 0, stream>>>(xb, wih0b, b0, gi);

    // phase 0: rec0 consumers + gi1 producers, co-resident (512 WGs, 2/CU)
    hipMemsetAsync(cnt, 0, 32768 + 262144, stream);   // cnt + hbuf (h(-1)=0)
    lstm_l0_fused_kernel<<<512, 256, 0, stream>>>(gi, wpk0, wpkI, b1p, hbuf,
                                                  out + 33554432, out + 33685504,
                                                  cnt);
    // phase 1: layer-1 recurrence (kernel boundary = gi1 visibility fence)
    hipMemsetAsync(cnt, 0, 32768 + 262144, stream);
    lstm_rec1_kernel<<<256, 256, 0, stream>>>(gi, wpk1, hbuf, out,
                                              out + 33554432 + 65536,
                                              out + 33685504 + 65536,
                                              cnt);
}

// Round 7
// 5483.578 us; speedup vs baseline: 1.0938x; 1.0938x over previous
//
#include <hip/hip_runtime.h>

typedef __attribute__((ext_vector_type(8))) short short8;
typedef __attribute__((ext_vector_type(4))) float f32x4;
typedef unsigned int uint32;
typedef unsigned long long u64;

// ---------- workspace layout (bytes) ----------
// gi: gemm0 output [512][64][4096] bf16, READ-ONLY afterwards (cached loads, L0).
// XB region (dead x-buffer space, x now read as fp32 by gemm0 directly):
//   holds the VIRGIN atomic rings — these bytes are NEVER touched by normal
//   cached loads/stores in any kernel of this launch (only SDMA memset +
//   agent-scope atomics), satisfying the virgin-atomics discipline that every
//   passing round (0/5/6) obeyed and rounds 2/3 violated.
#define OFF_GI    0ull                 // 268,435,456  bf16 gi0 (read-only)
#define OFF_Y0R   268435456ull         //   1,048,576  y0 ring [8][64][1024] bf16 (atomics)
#define OFF_H1B   269484032ull         //     262,144  h1 dbuf [2][64][1024] bf16 (atomics)
#define OFF_CNT2  269746176ull         //      32,768  int cnt[4][2048] (atomics)
#define OFF_WIH0  335544320ull         //   8,388,608  bf16 w_ih_0
#define OFF_WPKI  343932928ull         //   8,388,608  packed w_ih_1 gi1-fragments
#define OFF_WPK0  352321536ull         //   8,388,608  packed w_hh_0 frags
#define OFF_WPK1  360710144ull         //   8,388,608  packed w_hh_1 frags
#define OFF_B0    369098752ull         //      16,384  fp32 bias sum layer0 (natural)
#define OFF_B1    369115136ull         //      16,384  fp32 bias sum layer1 (PERM c*4+g)
#define WS_REQUIRED 369426432ull       // unchanged proven size

#define ALOAD(p)    __hip_atomic_load((p), __ATOMIC_RELAXED, __HIP_MEMORY_SCOPE_AGENT)
#define ASTOREV(p,v) __hip_atomic_store((p), (v), __ATOMIC_RELAXED, __HIP_MEMORY_SCOPE_AGENT)
#define AADD(p,v)   __hip_atomic_fetch_add((p), (v), __ATOMIC_RELAXED, __HIP_MEMORY_SCOPE_AGENT)
#define WD_ITERS 30000   // bounds worst-case broken-sync runtime well under 1 s

// ---------- helpers ----------
__device__ __forceinline__ unsigned short f2bf(float f) {
    union { float f; uint32 u; } v; v.f = f;
    uint32 u = v.u + 0x7FFFu + ((v.u >> 16) & 1u);   // round-to-nearest-even
    return (unsigned short)(u >> 16);
}
__device__ __forceinline__ float bf2f(unsigned short u) {
    union { uint32 u; float f; } v; v.u = ((uint32)u) << 16; return v.f;
}
__device__ __forceinline__ float sigmoidf_(float x) {
    return 1.0f / (1.0f + __expf(-x));
}
__device__ __forceinline__ float tanhf_(float x) {
    return 1.0f - 2.0f / (1.0f + __expf(2.0f * x));
}

// ---------- diagnostic ----------
__global__ void diag_kernel(float* out, float val) {
    if (blockIdx.x == 0 && threadIdx.x == 0) out[0] = val;
}

// ---------- small prep kernels ----------
__global__ void cast_bf16_kernel(const float* __restrict__ in,
                                 unsigned short* __restrict__ out, int n4) {
    int i = blockIdx.x * 256 + threadIdx.x;
    if (i < n4) {
        float4 v = ((const float4*)in)[i];
        ushort4 o;
        o.x = f2bf(v.x); o.y = f2bf(v.y); o.z = f2bf(v.z); o.w = f2bf(v.w);
        ((ushort4*)out)[i] = o;
    }
}

__global__ void bias_sum_kernel(const float* __restrict__ a,
                                const float* __restrict__ b,
                                float* __restrict__ o, int n) {
    int i = blockIdx.x * 256 + threadIdx.x;
    if (i < n) o[i] = a[i] + b[i];
}

// layer-1 bias gate-interleaved: o[c*4+g] = bih1[g*1024+c]+bhh1[g*1024+c]
__global__ void bias_perm_kernel(const float* __restrict__ a,
                                 const float* __restrict__ b,
                                 float* __restrict__ o) {
    int i = blockIdx.x * 256 + threadIdx.x;   // 4096
    int c = i >> 2, g = i & 3;
    o[i] = a[g * 1024 + c] + b[g * 1024 + c];
}

// Pack w_hh [4096][1024] fp32 into per-(WG,wave) MFMA B-fragment order, bf16.
__global__ void pack_whh_kernel(const float* __restrict__ whh,
                                unsigned short* __restrict__ out) {
    int o = blockIdx.x * 256 + threadIdx.x;   // 4,194,304 total
    int j  = o & 7;
    int l  = (o >> 3) & 63;
    int f  = (o >> 9) & 31;
    int wq = o >> 14;
    int w = wq >> 2, q = wq & 3;
    int g = f >> 3,  s = f & 7;
    int n = g * 1024 + w * 16 + (l & 15);
    int k = q * 256 + s * 32 + ((l >> 4)) * 8 + j;
    out[o] = f2bf(whh[(size_t)n * 1024 + k]);
}

// Pack w_ih_1 into gi1-GEMM B-fragments, gate-interleaved cols (round-5 certified).
__global__ void pack_wih1_frag_kernel(const float* __restrict__ wih1,
                                      unsigned short* __restrict__ out) {
    int o = blockIdx.x * 256 + threadIdx.x;   // 4,194,304 total
    int j  = o & 7;
    int l  = (o >> 3) & 63;
    int ks = (o >> 9) & 31;
    int wq = o >> 14;
    int w = wq >> 2, q = wq & 3;
    int np = w * 64 + q * 16 + (l & 15);
    int c = np >> 2, g = np & 3;
    int k = ks * 32 + ((l >> 4)) * 8 + j;
    out[o] = f2bf(wih1[(size_t)(g * 1024 + c) * 1024 + k]);
}

// ---------- layer-0 input GEMM, fp32-A variant ----------
// C[M,4096](bf16) = A_f32[M,1024] @ B_bf16[4096,1024]^T + bias.
// A is converted fp32->bf16 during LDS staging (x buffer read directly; no xb).
__global__ __launch_bounds__(256, 2) void gemm_bt_f32a_kernel(
    const float* __restrict__ A,
    const unsigned short* __restrict__ B,
    const float* __restrict__ bias,
    unsigned short* __restrict__ C) {
    __shared__ __align__(16) unsigned short As[128 * 64];
    __shared__ __align__(16) unsigned short Bs[128 * 64];
    const int tid = threadIdx.x;
    const int l = tid & 63;
    const int wv = tid >> 6;
    const int wm = wv >> 1, wn = wv & 1;
    const long bm = blockIdx.x, bn = blockIdx.y;

    f32x4 acc[4][4];
#pragma unroll
    for (int i = 0; i < 4; ++i)
#pragma unroll
        for (int j = 0; j < 4; ++j)
            acc[i][j] = (f32x4){0.f, 0.f, 0.f, 0.f};

    for (int k0 = 0; k0 < 1024; k0 += 64) {
#pragma unroll
        for (int ii = 0; ii < 4; ++ii) {
            int slot = ii * 256 + tid;
            int row = slot >> 3, csw = slot & 7;
            int cc = csw ^ (row & 7);
            const float* ap = A + (size_t)(bm * 128 + row) * 1024 + k0 + cc * 8;
            float4 va = ((const float4*)ap)[0];
            float4 vb = ((const float4*)ap)[1];
            ushort4 ua, ub;
            ua.x = f2bf(va.x); ua.y = f2bf(va.y); ua.z = f2bf(va.z); ua.w = f2bf(va.w);
            ub.x = f2bf(vb.x); ub.y = f2bf(vb.y); ub.z = f2bf(vb.z); ub.w = f2bf(vb.w);
            *(ushort4*)&As[slot * 8]     = ua;
            *(ushort4*)&As[slot * 8 + 4] = ub;
            *(uint4*)&Bs[slot * 8] =
                *(const uint4*)(B + (bn * 128 + row) * 1024 + k0 + cc * 8);
        }
        __syncthreads();
#pragma unroll
        for (int s = 0; s < 2; ++s) {
            short8 af[4], bfm[4];
#pragma unroll
            for (int i = 0; i < 4; ++i) {
                int row = wm * 64 + i * 16 + (l & 15);
                af[i] = *(const short8*)&As[(row * 8 + (((s * 4) + (l >> 4)) ^ (row & 7))) * 8];
            }
#pragma unroll
            for (int j = 0; j < 4; ++j) {
                int row = wn * 64 + j * 16 + (l & 15);
                bfm[j] = *(const short8*)&Bs[(row * 8 + (((s * 4) + (l >> 4)) ^ (row & 7))) * 8];
            }
#pragma unroll
            for (int i = 0; i < 4; ++i)
#pragma unroll
                for (int j = 0; j < 4; ++j)
                    acc[i][j] = __builtin_amdgcn_mfma_f32_16x16x32_bf16(
                        af[i], bfm[j], acc[i][j], 0, 0, 0);
        }
        __syncthreads();
    }
#pragma unroll
    for (int j = 0; j < 4; ++j) {
        float bj = bias[bn * 128 + wn * 64 + j * 16 + (l & 15)];
#pragma unroll
        for (int i = 0; i < 4; ++i) {
#pragma unroll
            for (int r = 0; r < 4; ++r) {
                long row = bm * 128 + wm * 64 + i * 16 + (l >> 4) * 4 + r;
                C[row * 4096 + bn * 128 + wn * 64 + j * 16 + (l & 15)] =
                    f2bf(acc[i][j][r] + bj);
            }
        }
    }
}

// ---------- fused dual-layer kernel ----------
// 512 WGs (2/CU): role 0 = layer-0 recurrence (round-0-exact, ring-published);
// role 1 = layer-1 recurrence with its gi1 slice computed IN-REGISTER from the
// staged y0 (round-5-certified gi1_tile math) during post-signal dead time.
// Cross-WG traffic ONLY on virgin regions (y0r/h1b/cnt). Forward-only deps:
//   L0(t) <- cg0[t-1], cg1[t-8] (ring slot protection, 8-step slack)
//   L1(t) <- cg1[t-1], cg0[t]   (y0(t) ready)
__global__ __launch_bounds__(256, 2) void lstm_fused2_kernel(
    const unsigned short* __restrict__ gi0,   // cached reads (L0 only)
    const unsigned short* __restrict__ wpk0,
    const unsigned short* __restrict__ wpk1,
    const unsigned short* __restrict__ wpkI,
    const float* __restrict__ b1p,
    unsigned short* y0r,                      // [8][64][1024] virgin ring
    unsigned short* h1b,                      // [2][64][1024] virgin dbuf
    float* __restrict__ yf, float* __restrict__ hn, float* __restrict__ cn,
    int* cnt)
{
    __shared__ __align__(16) char smem[53504];
    unsigned short* hs = (unsigned short*)smem;                          // 32 KB
    float (*red)[4][16][16] = (float (*)[4][16][16])(smem + 32768);      // 16 KB
    float* red2 = (float*)(smem + 49152);                                // 64x17 f32
    const int tid = threadIdx.x;
    const int l = tid & 63, q = tid >> 6;
    const int bid = blockIdx.x;
    const int role = bid >> 8;
    const int W = bid & 255;
    const int p = W >> 6, w = W & 63;
    int* cg0 = cnt + p * 2048;
    int* cg1 = cnt + p * 2048 + 1024;
    const int be = tid >> 4, je = tid & 15;
    const int hrow = p * 16 + be;
    const int hcol = w * 16 + je;

    if (role == 0) {
        // ================= layer 0 =================
        short8 bfr[4][8];
        {
            const unsigned short* wb = wpk0 + (size_t)((w * 4 + q) * 32) * 512 + (size_t)l * 8;
#pragma unroll
            for (int g = 0; g < 4; ++g)
#pragma unroll
                for (int s = 0; s < 8; ++s)
                    bfr[g][s] = *(const short8*)(wb + (g * 8 + s) * 512);
        }
        float c_state = 0.0f;

        for (int t = 0; t < 512; ++t) {
            const unsigned short* gp = gi0 + (size_t)t * 262144 + (size_t)hrow * 4096 + hcol;
            float g0 = bf2f(gp[0]);
            float g1 = bf2f(gp[1024]);
            float g2 = bf2f(gp[2048]);
            float g3 = bf2f(gp[3072]);

            if (tid == 0) {
                if (t > 0) {
                    int iters = 0;
                    while (ALOAD(&cg0[t - 1]) < 64) {
                        __builtin_amdgcn_s_sleep(2);
                        if (++iters > WD_ITERS) break;
                    }
                }
                if (t >= 8) {   // ring slot (t+1)&7 previously held y0(t-8)
                    int iters = 0;
                    while (ALOAD(&cg1[t - 8]) < 64) {
                        __builtin_amdgcn_s_sleep(2);
                        if (++iters > WD_ITERS) break;
                    }
                }
            }
            __syncthreads();                                              // B1

            // stage y0(t-1) = ring slot t&7, rows [16p,16p+16), XOR-swizzled
            {
                const u64* hp64 = (const u64*)(y0r + (size_t)(t & 7) * 65536);
#pragma unroll
                for (int ii = 0; ii < 8; ++ii) {
                    int slot = ii * 256 + tid;
                    int row = slot >> 7, cs = slot & 127;
                    int cc = cs ^ (row & 7);
                    size_t gidx = ((size_t)(p * 16 + row) * 1024 + (size_t)cc * 8) >> 2;
                    u64 lo = ALOAD(&hp64[gidx]);
                    u64 hi = ALOAD(&hp64[gidx + 1]);
                    *(u64*)&hs[slot * 8]     = lo;
                    *(u64*)&hs[slot * 8 + 4] = hi;
                }
            }
            __syncthreads();                                              // B2

            f32x4 acc[4];
#pragma unroll
            for (int g = 0; g < 4; ++g) acc[g] = (f32x4){0.f, 0.f, 0.f, 0.f};
            const int arow = l & 15;
#pragma unroll
            for (int s = 0; s < 8; ++s) {
                int chunk = q * 32 + s * 4 + (l >> 4);
                short8 af = *(const short8*)&hs[(arow * 128 + (chunk ^ (arow & 7))) * 8];
#pragma unroll
                for (int g = 0; g < 4; ++g)
                    acc[g] = __builtin_amdgcn_mfma_f32_16x16x32_bf16(
                        af, bfr[g][s], acc[g], 0, 0, 0);
            }
#pragma unroll
            for (int g = 0; g < 4; ++g)
#pragma unroll
                for (int r = 0; r < 4; ++r)
                    red[q][g][(l >> 4) * 4 + r][l & 15] = acc[g][r];
            __syncthreads();                                              // B3

            float gate_i = g0, gate_f = g1, gate_g = g2, gate_o = g3;
#pragma unroll
            for (int qq = 0; qq < 4; ++qq) {
                gate_i += red[qq][0][be][je];
                gate_f += red[qq][1][be][je];
                gate_g += red[qq][2][be][je];
                gate_o += red[qq][3][be][je];
            }
            float ig = sigmoidf_(gate_i);
            float fg = sigmoidf_(gate_f);
            float gg = tanhf_(gate_g);
            float og = sigmoidf_(gate_o);
            c_state = fg * c_state + ig * gg;
            float h_new = og * tanhf_(c_state);

            unsigned short hb = f2bf(h_new);
            {
                int v0 = hb;
                int v1 = __shfl_down(v0, 1);
                int v2 = __shfl_down(v0, 2);
                int v3 = __shfl_down(v0, 3);
                if ((l & 3) == 0) {
                    u64 u = (u64)(v0 & 0xffff) | ((u64)(v1 & 0xffff) << 16) |
                            ((u64)(v2 & 0xffff) << 32) | ((u64)(v3 & 0xffff) << 48);
                    u64* dst = (u64*)(y0r + (size_t)((t + 1) & 7) * 65536 +
                                      (size_t)hrow * 1024 + hcol);
                    ASTOREV(dst, u);
                }
            }
            if (t == 511) {
                hn[(size_t)hrow * 1024 + hcol] = h_new;
                cn[(size_t)hrow * 1024 + hcol] = c_state;
            }
            __syncthreads();                                              // B4 (drain)
            if (tid == 0) AADD(&cg0[t], 1);
        }
    } else {
        // ================= layer 1 =================
        short8 bfr[4][8];
        {
            const unsigned short* wb = wpk1 + (size_t)((w * 4 + q) * 32) * 512 + (size_t)l * 8;
#pragma unroll
            for (int g = 0; g < 4; ++g)
#pragma unroll
                for (int s = 0; s < 8; ++s)
                    bfr[g][s] = *(const short8*)(wb + (g * 8 + s) * 512);
        }
        const float4 bq = *(const float4*)&b1p[w * 64 + je * 4];   // gates i,f,g,o
        const unsigned short* wbI = wpkI + (size_t)(w * 4 + q) * 16384 + (size_t)l * 8;
        float c_state = 0.0f;
        const int arow = l & 15;

        // ---- prologue: gi1 gates for t=0 from y0(0) (ring slot 1) ----
        if (tid == 0) {
            int iters = 0;
            while (ALOAD(&cg0[0]) < 64) {
                __builtin_amdgcn_s_sleep(2);
                if (++iters > WD_ITERS) break;
            }
        }
        __syncthreads();
        {
            const u64* hp64 = (const u64*)(y0r + (size_t)1 * 65536);
#pragma unroll
            for (int ii = 0; ii < 8; ++ii) {
                int slot = ii * 256 + tid;
                int row = slot >> 7, cs = slot & 127;
                int cc = cs ^ (row & 7);
                size_t gidx = ((size_t)(p * 16 + row) * 1024 + (size_t)cc * 8) >> 2;
                u64 lo = ALOAD(&hp64[gidx]);
                u64 hi = ALOAD(&hp64[gidx + 1]);
                *(u64*)&hs[slot * 8]     = lo;
                *(u64*)&hs[slot * 8 + 4] = hi;
            }
        }
        __syncthreads();
        {
            f32x4 gacc = (f32x4){0.f, 0.f, 0.f, 0.f};
#pragma unroll 4
            for (int ks = 0; ks < 32; ++ks) {
                short8 bfk = *(const short8*)(wbI + ks * 512);
                short8 afk = *(const short8*)&hs[(arow * 128 + ((ks * 4 + (l >> 4)) ^ (arow & 7))) * 8];
                gacc = __builtin_amdgcn_mfma_f32_16x16x32_bf16(afk, bfk, gacc, 0, 0, 0);
            }
#pragma unroll
            for (int r = 0; r < 4; ++r)
                red2[(q * 16 + (l & 15)) * 17 + (l >> 4) * 4 + r] = gacc[r];
        }
        __syncthreads();

        for (int t = 0; t < 512; ++t) {
            if (t > 0 && tid == 0) {
                int iters = 0;
                while (ALOAD(&cg1[t - 1]) < 64) {
                    __builtin_amdgcn_s_sleep(2);
                    if (++iters > WD_ITERS) break;
                }
            }
            __syncthreads();                                              // B1

            // stage h1(t-1) from h1b slot t&1
            {
                const u64* hp64 = (const u64*)(h1b + (size_t)(t & 1) * 65536);
#pragma unroll
                for (int ii = 0; ii < 8; ++ii) {
                    int slot = ii * 256 + tid;
                    int row = slot >> 7, cs = slot & 127;
                    int cc = cs ^ (row & 7);
                    size_t gidx = ((size_t)(p * 16 + row) * 1024 + (size_t)cc * 8) >> 2;
                    u64 lo = ALOAD(&hp64[gidx]);
                    u64 hi = ALOAD(&hp64[gidx + 1]);
                    *(u64*)&hs[slot * 8]     = lo;
                    *(u64*)&hs[slot * 8 + 4] = hi;
                }
            }
            __syncthreads();                                              // B2

            f32x4 acc[4];
#pragma unroll
            for (int g = 0; g < 4; ++g) acc[g] = (f32x4){0.f, 0.f, 0.f, 0.f};
#pragma unroll
            for (int s = 0; s < 8; ++s) {
                int chunk = q * 32 + s * 4 + (l >> 4);
                short8 af = *(const short8*)&hs[(arow * 128 + (chunk ^ (arow & 7))) * 8];
#pragma unroll
                for (int g = 0; g < 4; ++g)
                    acc[g] = __builtin_amdgcn_mfma_f32_16x16x32_bf16(
                        af, bfr[g][s], acc[g], 0, 0, 0);
            }
#pragma unroll
            for (int g = 0; g < 4; ++g)
#pragma unroll
                for (int r = 0; r < 4; ++r)
                    red[q][g][(l >> 4) * 4 + r][l & 15] = acc[g][r];
            __syncthreads();                                              // B3

            // gates = in-LDS gi1 (from dead-time compute) + bias + h-partials
            float gate_i = red2[(je * 4 + 0) * 17 + be] + bq.x;
            float gate_f = red2[(je * 4 + 1) * 17 + be] + bq.y;
            float gate_g = red2[(je * 4 + 2) * 17 + be] + bq.z;
            float gate_o = red2[(je * 4 + 3) * 17 + be] + bq.w;
#pragma unroll
            for (int qq = 0; qq < 4; ++qq) {
                gate_i += red[qq][0][be][je];
                gate_f += red[qq][1][be][je];
                gate_g += red[qq][2][be][je];
                gate_o += red[qq][3][be][je];
            }
            float ig = sigmoidf_(gate_i);
            float fg = sigmoidf_(gate_f);
            float gg = tanhf_(gate_g);
            float og = sigmoidf_(gate_o);
            c_state = fg * c_state + ig * gg;
            float h_new = og * tanhf_(c_state);

            unsigned short hb = f2bf(h_new);
            {
                int v0 = hb;
                int v1 = __shfl_down(v0, 1);
                int v2 = __shfl_down(v0, 2);
                int v3 = __shfl_down(v0, 3);
                if ((l & 3) == 0) {
                    u64 u = (u64)(v0 & 0xffff) | ((u64)(v1 & 0xffff) << 16) |
                            ((u64)(v2 & 0xffff) << 32) | ((u64)(v3 & 0xffff) << 48);
                    u64* dst = (u64*)(h1b + (size_t)((t + 1) & 1) * 65536 +
                                      (size_t)hrow * 1024 + hcol);
                    ASTOREV(dst, u);
                }
            }
            yf[(size_t)t * 65536 + (size_t)hrow * 1024 + hcol] = h_new;
            if (t == 511) {
                hn[65536 + (size_t)hrow * 1024 + hcol] = h_new;
                cn[65536 + (size_t)hrow * 1024 + hcol] = c_state;
            }
            __syncthreads();                                              // B4 (drain)
            if (tid == 0) AADD(&cg1[t], 1);

            // ---- dead-time: gi1 gates for t+1 from y0(t+1) (slot (t+2)&7) ----
            if (t < 511) {
                if (tid == 0) {
                    int iters = 0;
                    while (ALOAD(&cg0[t + 1]) < 64) {
                        __builtin_amdgcn_s_sleep(2);
                        if (++iters > WD_ITERS) break;
                    }
                }
                __syncthreads();                                          // B5
                {
                    const u64* hp64 = (const u64*)(y0r + (size_t)((t + 2) & 7) * 65536);
#pragma unroll
                    for (int ii = 0; ii < 8; ++ii) {
                        int slot = ii * 256 + tid;
                        int row = slot >> 7, cs = slot & 127;
                        int cc = cs ^ (row & 7);
                        size_t gidx = ((size_t)(p * 16 + row) * 1024 + (size_t)cc * 8) >> 2;
                        u64 lo = ALOAD(&hp64[gidx]);
                        u64 hi = ALOAD(&hp64[gidx + 1]);
                        *(u64*)&hs[slot * 8]     = lo;
                        *(u64*)&hs[slot * 8 + 4] = hi;
                    }
                }
                __syncthreads();                                          // B6
                {
                    f32x4 gacc = (f32x4){0.f, 0.f, 0.f, 0.f};
#pragma unroll 4
                    for (int ks = 0; ks < 32; ++ks) {
                        short8 bfk = *(const short8*)(wbI + ks * 512);
                        short8 afk = *(const short8*)&hs[(arow * 128 + ((ks * 4 + (l >> 4)) ^ (arow & 7))) * 8];
                        gacc = __builtin_amdgcn_mfma_f32_16x16x32_bf16(afk, bfk, gacc, 0, 0, 0);
                    }
#pragma unroll
                    for (int r = 0; r < 4; ++r)
                        red2[(q * 16 + (l & 15)) * 17 + (l >> 4) * 4 + r] = gacc[r];
                }
                // next iteration's B1 orders red2/hs reuse
            }
        }
    }
}

// ---------- launcher ----------
extern "C" void kernel_launch(void* const* d_in, const int* in_sizes, int n_in,
                              void* d_out, int out_size, void* d_ws, size_t ws_size,
                              hipStream_t stream) {
    const float* x    = (const float*)d_in[0];
    const float* wih0 = (const float*)d_in[1];
    const float* whh0 = (const float*)d_in[2];
    const float* bih0 = (const float*)d_in[3];
    const float* bhh0 = (const float*)d_in[4];
    const float* wih1 = (const float*)d_in[5];
    const float* whh1 = (const float*)d_in[6];
    const float* bih1 = (const float*)d_in[7];
    const float* bhh1 = (const float*)d_in[8];
    float* out = (float*)d_out;

    if (ws_size < WS_REQUIRED) {
        diag_kernel<<<1, 64, 0, stream>>>(out, (float)(ws_size >> 20));
        return;
    }

    char* ws = (char*)d_ws;
    unsigned short* gi    = (unsigned short*)(ws + OFF_GI);
    unsigned short* y0r   = (unsigned short*)(ws + OFF_Y0R);
    unsigned short* h1b   = (unsigned short*)(ws + OFF_H1B);
    int*            cnt   = (int*)(ws + OFF_CNT2);
    unsigned short* wih0b = (unsigned short*)(ws + OFF_WIH0);
    unsigned short* wpkI  = (unsigned short*)(ws + OFF_WPKI);
    unsigned short* wpk0  = (unsigned short*)(ws + OFF_WPK0);
    unsigned short* wpk1  = (unsigned short*)(ws + OFF_WPK1);
    float*          b0    = (float*)(ws + OFF_B0);
    float*          b1p   = (float*)(ws + OFF_B1);

    // zero the virgin atomic block (y0 ring + h1 dbuf + counters): 1,343,488 B
    hipMemsetAsync(ws + OFF_Y0R, 0, 1343488, stream);

    // prep
    cast_bf16_kernel<<<4096, 256, 0, stream>>>(wih0, wih0b, 1048576);
    pack_wih1_frag_kernel<<<16384, 256, 0, stream>>>(wih1, wpkI);
    pack_whh_kernel<<<16384, 256, 0, stream>>>(whh0, wpk0);
    pack_whh_kernel<<<16384, 256, 0, stream>>>(whh1, wpk1);
    bias_sum_kernel<<<16, 256, 0, stream>>>(bih0, bhh0, b0, 4096);
    bias_perm_kernel<<<16, 256, 0, stream>>>(bih1, bhh1, b1p);

    // layer-0 input projection (x consumed directly as fp32)
    gemm_bt_f32a_kernel<<<dim3(256, 32), 256, 0, stream>>>(x, wih0b, b0, gi);

    // fused both-layer recurrence (512 WGs, 2/CU co-resident)
    lstm_fused2_kernel<<<512, 256, 0, stream>>>(gi, wpk0, wpk1, wpkI, b1p,
                                                y0r, h1b,
                                                out, out + 33554432, out + 33685504,
                                                cnt);
}